// Round 6
// baseline (262.355 us; speedup 1.0000x reference)
//
#include <hip/hip_runtime.h>
#include <hip/hip_bf16.h>
#include <cmath>

constexpr int D_MODEL = 1024;
constexpr int NHEAD   = 16;
constexpr int DH      = 64;
constexpr int BATCH   = 4;
constexpr int SEQ     = 2048;
constexpr int TOKENS  = BATCH * SEQ;          // 8192
constexpr float SCALE = 0.125f;               // 64^-0.5
// folded into q inside the QKV-GEMM rope epilogue: q' = (SCALE*log2e) * rot(q)
constexpr float QSF   = 0.125f * 1.44269504088896340736f;

typedef __attribute__((ext_vector_type(8))) short bf16x8;
typedef __attribute__((ext_vector_type(4))) short short4v;
typedef __attribute__((ext_vector_type(4))) float f32x4;
typedef __attribute__((ext_vector_type(4))) unsigned u32x4;

__device__ inline short f2bf(float f) {
    union { float f; unsigned u; } v; v.f = f;
    unsigned r = v.u + 0x7FFFu + ((v.u >> 16) & 1u);
    return (short)(r >> 16);
}
__device__ inline float bf2f(short s) {
    union { float f; unsigned u; } v;
    v.u = ((unsigned)(unsigned short)s) << 16;
    return v.f;
}
__device__ inline void llds16(const void* g, void* l) {
    __builtin_amdgcn_global_load_lds(
        (const __attribute__((address_space(1))) unsigned*)g,
        (__attribute__((address_space(3))) unsigned*)l, 16, 0, 0);
}

// ---------------------------------------------------------------------------
// Merged f32 -> bf16 convert for x, Wqkv_w, Wo_w (one launch, 3 segments)
// ---------------------------------------------------------------------------
constexpr int N8_X    = TOKENS * 1024 / 8;    // 1048576
constexpr int N8_WQKV = 3072 * 1024 / 8;      //  393216
constexpr int N8_WO   = 1024 * 1024 / 8;      //  131072

__global__ __launch_bounds__(256) void cvt3_bf16_kernel(
    const float* __restrict__ sx, const float* __restrict__ sq,
    const float* __restrict__ so,
    short* __restrict__ dx, short* __restrict__ dq, short* __restrict__ dw)
{
    int i = blockIdx.x * blockDim.x + threadIdx.x;
    const float* src; short* dst; int off;
    if (i < N8_X)                  { src = sx; dst = dx;  off = i; }
    else if (i < N8_X + N8_WQKV)   { src = sq; dst = dq;  off = i - N8_X; }
    else                           { src = so; dst = dw;  off = i - N8_X - N8_WQKV; }
    const float4* s = (const float4*)src + (size_t)off * 2;
    float4 a = s[0], b = s[1];
    bf16x8 v;
    v[0] = f2bf(a.x); v[1] = f2bf(a.y); v[2] = f2bf(a.z); v[3] = f2bf(a.w);
    v[4] = f2bf(b.x); v[5] = f2bf(b.y); v[6] = f2bf(b.z); v[7] = f2bf(b.w);
    *(bf16x8*)(dst + (size_t)off * 8) = v;
}

// ---------------------------------------------------------------------------
// r12: counted-vmcnt 3-deep-pipeline GEMM, XCD-chunked grid. BM=256, BN=128,
// BK=64, 512 thr (8 waves, 4M x 2N, 64x64 each). LDS 144KB: 3 x 48KB bufs.
// Per K-tile t (1 compute region, 2 barriers — r11's BAR1/BAR2 were pure
// lockstep overhead since both phases read one buffer):
//   16 ds_read_b128 frags + 32 MFMA (compiler-interleaved, setprio wrap)
//   lgkm0 + sched_barrier + BAR (buf t%3 free across waves)
//   stage tile t+3 -> buf t%3 (6 llds16)
//   vmcnt(12): drains tile t+1 ONLY — it has been in flight >=2 full
//     iterations (~1400cy > ~900cy HBM latency; r11's 1-iter slack was
//     the stall source). Tail: vmcnt(6)/(0) as the pipeline drains.
//   BAR
// XCD-chunk (T1): wg -> xcd = wg&7 owns a 4-bm stripe (2.1MB A <= 4MB L2)
// across all bn -> A fetched ~once device-wide; B streams per-XCD. Cuts
// QKV L2/L3 traffic ~800MB -> ~70MB. nwg%8==0 (768, 256) -> bijective.
// Staging swizzle: pre-swizzled global source + linear LDS dest (m173);
// llds16 dest is wave-uniform-base + lane*16 by construction (m104).
// ---------------------------------------------------------------------------
template<int ROPE, int OUTBF>
__global__ __launch_bounds__(512, 2) void gemm8p_mfma_kernel(
    const short* __restrict__ A, const short* __restrict__ B,
    const float* __restrict__ bias, void* __restrict__ C,
    const int* __restrict__ p, int M, int N, int K)
{
    extern __shared__ short smem[];
    constexpr int BUFSZ = (256 + 128) * 64;   // shorts per buffer

    const int tid  = threadIdx.x;
    const int w    = tid >> 6;
    const int lane = tid & 63;
    const int q16  = lane & 15;
    const int quad = lane >> 4;
    const int wm   = (w >> 1) * 64;    // 0,64,128,192
    const int wn   = (w & 1) * 64;     // 0,64
    const int NT   = K >> 6;

    // XCD-chunked block mapping: grid is 1-D, nwg = GX*GY, GX = M/256.
    const int GX  = M >> 8;
    const int cpx = GX >> 3;                   // bm-chunk per XCD
    const int wg  = blockIdx.x;
    const int xcd = wg & 7;
    const int r_  = wg >> 3;
    const int bm  = (xcd * cpx + (r_ % cpx)) * 256;
    const int bn  = (r_ / cpx) * 128;

    const int rowbase = tid >> 3;      // 0..63
    const int ch      = tid & 7;
    const int chs     = ch ^ (rowbase & 7);  // pre-swizzled source chunk

    auto stage = [&](int buf, int tt) {
        const int k0 = tt * 64;
        short* base  = smem + buf * BUFSZ;
        #pragma unroll
        for (int i = 0; i < 4; i++) {
            int r = i * 64 + rowbase;
            llds16(A + (size_t)(bm + r) * K + k0 + chs * 8,
                   base + r * 64 + ch * 8);
        }
        short* bbase = base + 256 * 64;
        #pragma unroll
        for (int i = 0; i < 2; i++) {
            int r = i * 64 + rowbase;
            llds16(B + (size_t)(bn + r) * K + k0 + chs * 8,
                   bbase + r * 64 + ch * 8);
        }
    };

    f32x4 acc[4][4];
    #pragma unroll
    for (int i = 0; i < 4; i++)
        #pragma unroll
        for (int j = 0; j < 4; j++) acc[i][j] = (f32x4){0.f, 0.f, 0.f, 0.f};

    // prologue: tiles 0,1,2 in flight; drain tile 0 only (12 = 2x6 remain)
    stage(0, 0);
    stage(1, 1);
    stage(2, 2);
    asm volatile("s_waitcnt vmcnt(12)" ::: "memory");
    asm volatile("s_barrier" ::: "memory");

    int c = 0;
    for (int t = 0; t < NT; t++) {
        const short* as = smem + c * BUFSZ;
        const short* bs = as + 256 * 64;

        bf16x8 af[2][4], bfr[2][4];
        #pragma unroll
        for (int ks = 0; ks < 2; ks++) {
            const int sw = (ks * 4 + quad) ^ (q16 & 7);
            #pragma unroll
            for (int i = 0; i < 4; i++) {
                af[ks][i]  = *(const bf16x8*)&as[(wm + i * 16 + q16) * 64 + sw * 8];
                bfr[ks][i] = *(const bf16x8*)&bs[(wn + i * 16 + q16) * 64 + sw * 8];
            }
        }
        __builtin_amdgcn_s_setprio(1);
        #pragma unroll
        for (int ks = 0; ks < 2; ks++)
            #pragma unroll
            for (int mb = 0; mb < 4; mb++)
                #pragma unroll
                for (int nb = 0; nb < 4; nb++)
                    acc[mb][nb] = __builtin_amdgcn_mfma_f32_16x16x32_bf16(
                        af[ks][mb], bfr[ks][nb], acc[mb][nb], 0, 0, 0);
        __builtin_amdgcn_s_setprio(0);

        if (t + 1 < NT) {
            asm volatile("s_waitcnt lgkmcnt(0)" ::: "memory");
            __builtin_amdgcn_sched_barrier(0);
            asm volatile("s_barrier" ::: "memory");       // buf c free
            if (t + 3 < NT) {
                stage(c, t + 3);
                asm volatile("s_waitcnt vmcnt(12)" ::: "memory");
            } else if (t + 2 < NT) {
                asm volatile("s_waitcnt vmcnt(6)" ::: "memory");
            } else {
                asm volatile("s_waitcnt vmcnt(0)" ::: "memory");
            }
            asm volatile("s_barrier" ::: "memory");       // tile t+1 ready
        }
        c = (c == 2) ? 0 : c + 1;
    }

    if (ROPE && (bn + wn) < 2 * D_MODEL) {
        // q or k head: rotate pairs (nb, nb+2) = dims (i, i+32), i = nb*16+q16
        const float sf = (bn + wn) < D_MODEL ? QSF : 1.0f;
        float posv[4][4];
        #pragma unroll
        for (int mb = 0; mb < 4; mb++) {
            const int rm = bm + wm + mb * 16 + quad * 4;
            #pragma unroll
            for (int r = 0; r < 4; r++) posv[mb][r] = (float)p[rm + r];
        }
        #pragma unroll
        for (int nb = 0; nb < 2; nb++) {
            const int i   = nb * 16 + q16;
            const int cn0 = bn + wn + i;
            const int cn1 = cn0 + 32;
            const float b0 = bias[cn0], b1 = bias[cn1];
            const float fr = __builtin_amdgcn_exp2f((float)i * -0.4152410118609203f)
                             * 0.15915494309189535f;
            #pragma unroll
            for (int mb = 0; mb < 4; mb++) {
                const int rm = bm + wm + mb * 16 + quad * 4;
                #pragma unroll
                for (int r = 0; r < 4; r++) {
                    float t = posv[mb][r] * fr;
                    t -= floorf(t);
                    float sn = __builtin_amdgcn_sinf(t);
                    float c2 = __builtin_amdgcn_cosf(t);
                    float v0 = acc[mb][nb][r]     + b0;
                    float v1 = acc[mb][nb + 2][r] + b1;
                    ((short*)C)[(size_t)(rm + r) * N + cn0] =
                        f2bf(fmaf(v0, c2,  v1 * sn) * sf);
                    ((short*)C)[(size_t)(rm + r) * N + cn1] =
                        f2bf(fmaf(v1, c2, -v0 * sn) * sf);
                }
            }
        }
        return;
    }

    #pragma unroll
    for (int nb = 0; nb < 4; nb++) {
        const int cn = bn + wn + nb * 16 + q16;
        const float bv = bias[cn];
        #pragma unroll
        for (int mb = 0; mb < 4; mb++) {
            const int rm = bm + wm + mb * 16 + quad * 4;
            #pragma unroll
            for (int r = 0; r < 4; r++) {
                float v = acc[mb][nb][r] + bv;
                if (OUTBF)
                    ((short*)C)[(size_t)(rm + r) * N + cn] = f2bf(v);
                else
                    ((float*)C)[(size_t)(rm + r) * N + cn] = v;
            }
        }
    }
}

// ---------------------------------------------------------------------------
// MFMA flash attention v5 (r7 exact — best measured 87.4us).
// S^T = K @ Q^T (verified layouts m89/m91/m120). P never touches LDS: the
// quad-group key redistribution is done in-register — Vs key axis is stored
// PERMUTED (pi(ks,quad,j) = 16*(2ks+(quad&1)) + 8*(quad>>1) + j), making the
// exchange exactly v_permlane16_swap_b32 (vdst rows 1,3 <-> vsrc rows 0,2).
// Double-buffered K/V, one barrier/tile, no online max (bounded scores);
// 64 q/wave; scale pre-folded in q; bare v_exp_f32; bh = gid&63 L2 swizzle.
// LDS 32KB/block -> 2 blocks/CU (grid 512 = 2/CU exactly).
// ---------------------------------------------------------------------------
__global__ __launch_bounds__(256, 2) void attn_mfma_kernel(
    const short* __restrict__ qkv, short* __restrict__ out)
{
    __shared__ short Ks[2][64 * 64];   // [buf][key-row][dim-chunk swz]
    __shared__ short Vs[2][64 * 64];   // [buf][dim-row][key-chunk swz, pi-permuted]

    const int tid  = threadIdx.x;
    const int w    = tid >> 6;
    const int lane = tid & 63;
    const int q16  = lane & 15;
    const int quad = lane >> 4;
    const int gid  = blockIdx.x;
    const int bh   = gid & 63;       // XCD co-location for K/V reuse
    const int qblk = gid >> 6;       // 0..7
    const int b    = bh >> 4;
    const int h    = bh & 15;
    const int qtok0 = qblk * 256 + w * 64;

    // Q fragments (pre-scaled by the QKV-GEMM rope epilogue)
    bf16x8 qf[4][2];
    #pragma unroll
    for (int qb = 0; qb < 4; qb++) {
        const short* Qrow =
            qkv + (size_t)(b * SEQ + qtok0 + qb * 16 + q16) * 3072 + h * 64;
        qf[qb][0] = *(const bf16x8*)(Qrow + quad * 8);
        qf[qb][1] = *(const bf16x8*)(Qrow + 32 + quad * 8);
    }

    f32x4 o[4][4];
    #pragma unroll
    for (int qb = 0; qb < 4; qb++)
        #pragma unroll
        for (int md = 0; md < 4; md++) o[qb][md] = (f32x4){0.f, 0.f, 0.f, 0.f};
    float lsum[4] = {0.f, 0.f, 0.f, 0.f};

    const short* Kg = qkv + (size_t)b * SEQ * 3072 + 1024 + h * 64;
    const short* Vg = Kg + 1024;

    // staging constants
    const int krow = w * 16 + (lane >> 3);          // K row this lane fetches
    const int kc   = (lane & 7) ^ (krow & 7);       // swizzled source chunk
    const int vkey = (tid & 31) * 2;                // V: 2 keys per thread
    const int vdb  = (tid >> 5) * 8;                // V: 8 dims per thread
    // pi-permuted logical chunk for this thread's key pair (vkey even ->
    // vkey,vkey+1 share a chunk, at positions vkey&7, (vkey&7)+1)
    const int vL   = ((vkey >> 5) << 2) | (((vkey >> 3) & 1) << 1) | ((vkey >> 4) & 1);

    // V perm-pack + swizzled write: row = vdb+j (row&7 == j), chunk' = vL^j
    auto vwrite = [&](int buf, const uint4& a, const uint4& bb) {
        #pragma unroll
        for (int j = 0; j < 8; j++) {
            unsigned lo = (j & 1) ? 0x07060302u : 0x05040100u;
            unsigned sa = (&a.x)[j >> 1], sb = (&bb.x)[j >> 1];
            *(unsigned*)&Vs[buf][(vdb + j) * 64 + ((vL ^ j) << 3) + (vkey & 7)] =
                __builtin_amdgcn_perm(sb, sa, lo);
        }
    };

    // ---- prologue: stage tile 0 into buf 0 ----
    {
        llds16(Kg + (size_t)krow * 3072 + kc * 8, &Ks[0][(w * 16) * 64]);
        llds16(Kg + (size_t)(krow + 8) * 3072 + kc * 8, &Ks[0][(w * 16 + 8) * 64]);
        const short* vsrc = Vg + (size_t)vkey * 3072 + vdb;
        uint4 a  = *(const uint4*)vsrc;
        uint4 bb = *(const uint4*)(vsrc + 3072);
        vwrite(0, a, bb);
    }
    __syncthreads();

    int cur = 0;
    for (int t = 0; t < SEQ / 64; t++) {
        // prefetch tile t+1 into buf cur^1
        uint4 pva, pvb;
        const bool pf = (t < SEQ / 64 - 1);
        if (pf) {
            const int ktn = (t + 1) * 64;
            llds16(Kg + (size_t)(ktn + krow) * 3072 + kc * 8,
                   &Ks[cur ^ 1][(w * 16) * 64]);
            llds16(Kg + (size_t)(ktn + krow + 8) * 3072 + kc * 8,
                   &Ks[cur ^ 1][(w * 16 + 8) * 64]);
            const short* vsrc = Vg + (size_t)(ktn + vkey) * 3072 + vdb;
            pva = *(const uint4*)vsrc;
            pvb = *(const uint4*)(vsrc + 3072);
        }

        // fragment loads from buf cur (af/av share the address expression)
        bf16x8 af[4][2], av[4][2];
        #pragma unroll
        for (int mb = 0; mb < 4; mb++) {
            #pragma unroll
            for (int ks = 0; ks < 2; ks++) {
                int c = (((ks * 4 + quad) ^ (q16 & 7))) * 8;
                af[mb][ks] = *(const bf16x8*)&Ks[cur][(mb * 16 + q16) * 64 + c];
                av[mb][ks] = *(const bf16x8*)&Vs[cur][(mb * 16 + q16) * 64 + c];
            }
        }

        #pragma unroll
        for (int qb = 0; qb < 4; qb++) {
            // scores S^T (A = K, B = Q^T); scale already inside q
            f32x4 sc[4];
            #pragma unroll
            for (int mb = 0; mb < 4; mb++) {
                f32x4 c = {0.f, 0.f, 0.f, 0.f};
                c = __builtin_amdgcn_mfma_f32_16x16x32_bf16(af[mb][0], qf[qb][0], c, 0, 0, 0);
                c = __builtin_amdgcn_mfma_f32_16x16x32_bf16(af[mb][1], qf[qb][1], c, 0, 0, 0);
                sc[mb] = c;
            }
            float ltile = 0.f;
            unsigned da[4], db[4];
            // exp + pack mb 0,1 (keys for PV ks=0)
            #pragma unroll
            for (int mb = 0; mb < 2; mb++) {
                float p0 = __builtin_amdgcn_exp2f(sc[mb][0]);
                float p1 = __builtin_amdgcn_exp2f(sc[mb][1]);
                float p2 = __builtin_amdgcn_exp2f(sc[mb][2]);
                float p3 = __builtin_amdgcn_exp2f(sc[mb][3]);
                ltile += (p0 + p1) + (p2 + p3);
                asm("v_cvt_pk_bf16_f32 %0, %1, %2" : "=v"(da[mb]) : "v"(p0), "v"(p1));
                asm("v_cvt_pk_bf16_f32 %0, %1, %2" : "=v"(db[mb]) : "v"(p2), "v"(p3));
            }
            // in-register quad-pair exchange: vdst rows 1,3 <-> vsrc rows 0,2
            asm("v_permlane16_swap_b32 %0, %1" : "+v"(da[0]), "+v"(da[1]));
            asm("v_permlane16_swap_b32 %0, %1" : "+v"(db[0]), "+v"(db[1]));
            union { u32x4 u; bf16x8 v; } pb0;
            pb0.u = (u32x4){da[0], db[0], da[1], db[1]};
            // exp + pack mb 2,3 (overlaps PV ks=0 below)
            #pragma unroll
            for (int mb = 2; mb < 4; mb++) {
                float p0 = __builtin_amdgcn_exp2f(sc[mb][0]);
                float p1 = __builtin_amdgcn_exp2f(sc[mb][1]);
                float p2 = __builtin_amdgcn_exp2f(sc[mb][2]);
                float p3 = __builtin_amdgcn_exp2f(sc[mb][3]);
                ltile += (p0 + p1) + (p2 + p3);
                asm("v_cvt_pk_bf16_f32 %0, %1, %2" : "=v"(da[mb]) : "v"(p0), "v"(p1));
                asm("v_cvt_pk_bf16_f32 %0, %1, %2" : "=v"(db[mb]) : "v"(p2), "v"(p3));
            }
            // PV ks=0
            #pragma unroll
            for (int md = 0; md < 4; md++)
                o[qb][md] = __builtin_amdgcn_mfma_f32_16x16x32_bf16(
                    av[md][0], pb0.v, o[qb][md], 0, 0, 0);
            asm("v_permlane16_swap_b32 %0, %1" : "+v"(da[2]), "+v"(da[3]));
            asm("v_permlane16_swap_b32 %0, %1" : "+v"(db[2]), "+v"(db[3]));
            union { u32x4 u; bf16x8 v; } pb1;
            pb1.u = (u32x4){da[2], db[2], da[3], db[3]};
            // PV ks=1
            #pragma unroll
            for (int md = 0; md < 4; md++)
                o[qb][md] = __builtin_amdgcn_mfma_f32_16x16x32_bf16(
                    av[md][1], pb1.v, o[qb][md], 0, 0, 0);
            lsum[qb] += ltile;
        }

        // write prefetched V into buf cur^1 after compute
        if (pf) vwrite(cur ^ 1, pva, pvb);
        __syncthreads();
        cur ^= 1;
    }

    // epilogue: cross-quad l reduction, normalize, store bf16
    #pragma unroll
    for (int qb = 0; qb < 4; qb++) {
        float l = lsum[qb];
        l += __shfl_xor(l, 16);
        l += __shfl_xor(l, 32);
        float inv = 1.f / l;
        short* orow = out + (size_t)(b * SEQ + qtok0 + qb * 16 + q16) * 1024
                      + h * 64 + quad * 4;
        #pragma unroll
        for (int md = 0; md < 4; md++) {
            short4v t;
            t[0] = f2bf(o[qb][md][0] * inv);
            t[1] = f2bf(o[qb][md][1] * inv);
            t[2] = f2bf(o[qb][md][2] * inv);
            t[3] = f2bf(o[qb][md][3] * inv);
            *(short4v*)(orow + md * 16) = t;
        }
    }
}

// ---------------------------------------------------------------------------
extern "C" void kernel_launch(void* const* d_in, const int* in_sizes, int n_in,
                              void* d_out, int out_size, void* d_ws, size_t ws_size,
                              hipStream_t stream)
{
    (void)in_sizes; (void)n_in; (void)out_size; (void)ws_size;
    const float* x      = (const float*)d_in[0];
    const int*   p      = (const int*)  d_in[1];
    const float* Wqkv_w = (const float*)d_in[2];
    const float* Wqkv_b = (const float*)d_in[3];
    const float* Wo_w   = (const float*)d_in[4];
    const float* Wo_b   = (const float*)d_in[5];
    float* out = (float*)d_out;

    short* xb     = (short*)d_ws;                         // 16 MiB
    short* wqkvb  = xb + (size_t)TOKENS * 1024;           // 6 MiB
    short* wob    = wqkvb + (size_t)3072 * 1024;          // 2 MiB
    short* qkvb   = wob + (size_t)1024 * 1024;            // 48 MiB
    short* attnob = qkvb + (size_t)TOKENS * 3072;         // 16 MiB

    dim3 blk(256);
    constexpr int GEMM_LDS = 3 * (256 + 128) * 64 * 2;    // 147456 B

    cvt3_bf16_kernel<<<dim3((N8_X + N8_WQKV + N8_WO) / 256), blk, 0, stream>>>(
        x, Wqkv_w, Wo_w, xb, wqkvb, wob);

    static bool attr_done = false;
    if (!attr_done) {
        hipFuncSetAttribute(reinterpret_cast<const void*>(&gemm8p_mfma_kernel<1, 1>),
                            hipFuncAttributeMaxDynamicSharedMemorySize, GEMM_LDS);
        hipFuncSetAttribute(reinterpret_cast<const void*>(&gemm8p_mfma_kernel<0, 0>),
                            hipFuncAttributeMaxDynamicSharedMemorySize, GEMM_LDS);
        attr_done = true;
    }

    // QKV GEMM: M=8192 N=3072 K=1024; 1-D grid 32*24 = 768 (nwg%8==0)
    gemm8p_mfma_kernel<1, 1><<<dim3((TOKENS / 256) * (3072 / 128)), dim3(512),
                               GEMM_LDS, stream>>>(
        xb, wqkvb, Wqkv_b, qkvb, p, TOKENS, 3072, 1024);

    attn_mfma_kernel<<<dim3(512), blk, 0, stream>>>(qkvb, attnob);

    // Wo GEMM: M=8192 N=1024 K=1024; 1-D grid 32*8 = 256 (1 exact round)
    gemm8p_mfma_kernel<0, 0><<<dim3((TOKENS / 256) * (1024 / 128)), dim3(512),
                               GEMM_LDS, stream>>>(
        attnob, wob, Wo_b, out, nullptr, TOKENS, 1024, 1024);
}

// Round 7
// 258.536 us; speedup vs baseline: 1.0148x; 1.0148x over previous
//
#include <hip/hip_runtime.h>
#include <hip/hip_bf16.h>
#include <cmath>

constexpr int D_MODEL = 1024;
constexpr int NHEAD   = 16;
constexpr int DH      = 64;
constexpr int BATCH   = 4;
constexpr int SEQ     = 2048;
constexpr int TOKENS  = BATCH * SEQ;          // 8192
constexpr float SCALE = 0.125f;               // 64^-0.5
// folded into q inside the QKV-GEMM rope epilogue: q' = (SCALE*log2e) * rot(q)
constexpr float QSF   = 0.125f * 1.44269504088896340736f;

typedef __attribute__((ext_vector_type(8))) short bf16x8;
typedef __attribute__((ext_vector_type(4))) short short4v;
typedef __attribute__((ext_vector_type(4))) float f32x4;
typedef __attribute__((ext_vector_type(4))) unsigned u32x4;

__device__ inline short f2bf(float f) {
    union { float f; unsigned u; } v; v.f = f;
    unsigned r = v.u + 0x7FFFu + ((v.u >> 16) & 1u);
    return (short)(r >> 16);
}
__device__ inline float bf2f(short s) {
    union { float f; unsigned u; } v;
    v.u = ((unsigned)(unsigned short)s) << 16;
    return v.f;
}
__device__ inline void llds16(const void* g, void* l) {
    __builtin_amdgcn_global_load_lds(
        (const __attribute__((address_space(1))) unsigned*)g,
        (__attribute__((address_space(3))) unsigned*)l, 16, 0, 0);
}

// ---------------------------------------------------------------------------
// Merged f32 -> bf16 convert for x, Wqkv_w, Wo_w (one launch, 3 segments)
// ---------------------------------------------------------------------------
constexpr int N8_X    = TOKENS * 1024 / 8;    // 1048576
constexpr int N8_WQKV = 3072 * 1024 / 8;      //  393216
constexpr int N8_WO   = 1024 * 1024 / 8;      //  131072

__global__ __launch_bounds__(256) void cvt3_bf16_kernel(
    const float* __restrict__ sx, const float* __restrict__ sq,
    const float* __restrict__ so,
    short* __restrict__ dx, short* __restrict__ dq, short* __restrict__ dw)
{
    int i = blockIdx.x * blockDim.x + threadIdx.x;
    const float* src; short* dst; int off;
    if (i < N8_X)                  { src = sx; dst = dx;  off = i; }
    else if (i < N8_X + N8_WQKV)   { src = sq; dst = dq;  off = i - N8_X; }
    else                           { src = so; dst = dw;  off = i - N8_X - N8_WQKV; }
    const float4* s = (const float4*)src + (size_t)off * 2;
    float4 a = s[0], b = s[1];
    bf16x8 v;
    v[0] = f2bf(a.x); v[1] = f2bf(a.y); v[2] = f2bf(a.z); v[3] = f2bf(a.w);
    v[4] = f2bf(b.x); v[5] = f2bf(b.y); v[6] = f2bf(b.z); v[7] = f2bf(b.w);
    *(bf16x8*)(dst + (size_t)off * 8) = v;
}

// ---------------------------------------------------------------------------
// r12 GEMM (unchanged in r13): counted-vmcnt 3-deep pipeline, XCD-chunked
// grid. BM=256, BN=128, BK=64, 512 thr (8 waves, 4M x 2N). LDS 144KB: 3
// bufs. vmcnt(12) at the boundary keeps 2 full iterations of slack. XCD
// chunk: wg&7 owns a bm-stripe (A resident in that XCD's L2). Measured
// equal to the r10 128^2 structure (262.3 vs 261.5) — kept as baseline.
// ---------------------------------------------------------------------------
template<int ROPE, int OUTBF>
__global__ __launch_bounds__(512, 2) void gemm8p_mfma_kernel(
    const short* __restrict__ A, const short* __restrict__ B,
    const float* __restrict__ bias, void* __restrict__ C,
    const int* __restrict__ p, int M, int N, int K)
{
    extern __shared__ short smem[];
    constexpr int BUFSZ = (256 + 128) * 64;   // shorts per buffer

    const int tid  = threadIdx.x;
    const int w    = tid >> 6;
    const int lane = tid & 63;
    const int q16  = lane & 15;
    const int quad = lane >> 4;
    const int wm   = (w >> 1) * 64;    // 0,64,128,192
    const int wn   = (w & 1) * 64;     // 0,64
    const int NT   = K >> 6;

    // XCD-chunked block mapping: grid is 1-D, nwg = GX*GY, GX = M/256.
    const int GX  = M >> 8;
    const int cpx = GX >> 3;                   // bm-chunk per XCD
    const int wg  = blockIdx.x;
    const int xcd = wg & 7;
    const int r_  = wg >> 3;
    const int bm  = (xcd * cpx + (r_ % cpx)) * 256;
    const int bn  = (r_ / cpx) * 128;

    const int rowbase = tid >> 3;      // 0..63
    const int ch      = tid & 7;
    const int chs     = ch ^ (rowbase & 7);  // pre-swizzled source chunk

    auto stage = [&](int buf, int tt) {
        const int k0 = tt * 64;
        short* base  = smem + buf * BUFSZ;
        #pragma unroll
        for (int i = 0; i < 4; i++) {
            int r = i * 64 + rowbase;
            llds16(A + (size_t)(bm + r) * K + k0 + chs * 8,
                   base + r * 64 + ch * 8);
        }
        short* bbase = base + 256 * 64;
        #pragma unroll
        for (int i = 0; i < 2; i++) {
            int r = i * 64 + rowbase;
            llds16(B + (size_t)(bn + r) * K + k0 + chs * 8,
                   bbase + r * 64 + ch * 8);
        }
    };

    f32x4 acc[4][4];
    #pragma unroll
    for (int i = 0; i < 4; i++)
        #pragma unroll
        for (int j = 0; j < 4; j++) acc[i][j] = (f32x4){0.f, 0.f, 0.f, 0.f};

    // prologue: tiles 0,1,2 in flight; drain tile 0 only (12 = 2x6 remain)
    stage(0, 0);
    stage(1, 1);
    stage(2, 2);
    asm volatile("s_waitcnt vmcnt(12)" ::: "memory");
    asm volatile("s_barrier" ::: "memory");

    int c = 0;
    for (int t = 0; t < NT; t++) {
        const short* as = smem + c * BUFSZ;
        const short* bs = as + 256 * 64;

        bf16x8 af[2][4], bfr[2][4];
        #pragma unroll
        for (int ks = 0; ks < 2; ks++) {
            const int sw = (ks * 4 + quad) ^ (q16 & 7);
            #pragma unroll
            for (int i = 0; i < 4; i++) {
                af[ks][i]  = *(const bf16x8*)&as[(wm + i * 16 + q16) * 64 + sw * 8];
                bfr[ks][i] = *(const bf16x8*)&bs[(wn + i * 16 + q16) * 64 + sw * 8];
            }
        }
        __builtin_amdgcn_s_setprio(1);
        #pragma unroll
        for (int ks = 0; ks < 2; ks++)
            #pragma unroll
            for (int mb = 0; mb < 4; mb++)
                #pragma unroll
                for (int nb = 0; nb < 4; nb++)
                    acc[mb][nb] = __builtin_amdgcn_mfma_f32_16x16x32_bf16(
                        af[ks][mb], bfr[ks][nb], acc[mb][nb], 0, 0, 0);
        __builtin_amdgcn_s_setprio(0);

        if (t + 1 < NT) {
            asm volatile("s_waitcnt lgkmcnt(0)" ::: "memory");
            __builtin_amdgcn_sched_barrier(0);
            asm volatile("s_barrier" ::: "memory");       // buf c free
            if (t + 3 < NT) {
                stage(c, t + 3);
                asm volatile("s_waitcnt vmcnt(12)" ::: "memory");
            } else if (t + 2 < NT) {
                asm volatile("s_waitcnt vmcnt(6)" ::: "memory");
            } else {
                asm volatile("s_waitcnt vmcnt(0)" ::: "memory");
            }
            asm volatile("s_barrier" ::: "memory");       // tile t+1 ready
        }
        c = (c == 2) ? 0 : c + 1;
    }

    if (ROPE && (bn + wn) < 2 * D_MODEL) {
        // q or k head: rotate pairs (nb, nb+2) = dims (i, i+32), i = nb*16+q16
        const float sf = (bn + wn) < D_MODEL ? QSF : 1.0f;
        float posv[4][4];
        #pragma unroll
        for (int mb = 0; mb < 4; mb++) {
            const int rm = bm + wm + mb * 16 + quad * 4;
            #pragma unroll
            for (int r = 0; r < 4; r++) posv[mb][r] = (float)p[rm + r];
        }
        #pragma unroll
        for (int nb = 0; nb < 2; nb++) {
            const int i   = nb * 16 + q16;
            const int cn0 = bn + wn + i;
            const int cn1 = cn0 + 32;
            const float b0 = bias[cn0], b1 = bias[cn1];
            const float fr = __builtin_amdgcn_exp2f((float)i * -0.4152410118609203f)
                             * 0.15915494309189535f;
            #pragma unroll
            for (int mb = 0; mb < 4; mb++) {
                const int rm = bm + wm + mb * 16 + quad * 4;
                #pragma unroll
                for (int r = 0; r < 4; r++) {
                    float t = posv[mb][r] * fr;
                    t -= floorf(t);
                    float sn = __builtin_amdgcn_sinf(t);
                    float c2 = __builtin_amdgcn_cosf(t);
                    float v0 = acc[mb][nb][r]     + b0;
                    float v1 = acc[mb][nb + 2][r] + b1;
                    ((short*)C)[(size_t)(rm + r) * N + cn0] =
                        f2bf(fmaf(v0, c2,  v1 * sn) * sf);
                    ((short*)C)[(size_t)(rm + r) * N + cn1] =
                        f2bf(fmaf(v1, c2, -v0 * sn) * sf);
                }
            }
        }
        return;
    }

    #pragma unroll
    for (int nb = 0; nb < 4; nb++) {
        const int cn = bn + wn + nb * 16 + q16;
        const float bv = bias[cn];
        #pragma unroll
        for (int mb = 0; mb < 4; mb++) {
            const int rm = bm + wm + mb * 16 + quad * 4;
            #pragma unroll
            for (int r = 0; r < 4; r++) {
                float v = acc[mb][nb][r] + bv;
                if (OUTBF)
                    ((short*)C)[(size_t)(rm + r) * N + cn] = f2bf(v);
                else
                    ((float*)C)[(size_t)(rm + r) * N + cn] = v;
            }
        }
    }
}

// ---------------------------------------------------------------------------
// MFMA flash attention v8 (r13). r7 body + two changes:
//  - amdgpu_waves_per_eu(2,2): the grid caps real occupancy at 2 waves/SIMD
//    (512 blocks = 2 blocks/CU), but launch_bounds(256,2) let LLVM target 4
//    waves/SIMD -> it pinned VGPR at 128 (observed in every round) and paid
//    by serializing the QK->exp->cvt->permlane->PV chain. (2,2) gives the
//    regalloc the full 256-VGPR budget for the occupancy we actually have.
//    This is also the suspected reason r9's pipeline was flat at 128 VGPR.
//  - qb software pipeline (r9 structure, no setprio): QK(qb+1) issued before
//    softmax VALU of qb; sc is a 2-deep ping-pong (static index under full
//    unroll).
// Unchanged: S^T = K @ Q^T; P in-register (cvt_pk + permlane16_swap, Vs key
// axis pi-permuted); double-buffered K/V; one barrier/tile; no online max
// (bounded scores); bh = gid&63 L2 swizzle; LDS 32KB/block.
// ---------------------------------------------------------------------------
__global__ __launch_bounds__(256)
__attribute__((amdgpu_waves_per_eu(2, 2)))
void attn_mfma_kernel(
    const short* __restrict__ qkv, short* __restrict__ out)
{
    __shared__ short Ks[2][64 * 64];   // [buf][key-row][dim-chunk swz]
    __shared__ short Vs[2][64 * 64];   // [buf][dim-row][key-chunk swz, pi-permuted]

    const int tid  = threadIdx.x;
    const int w    = tid >> 6;
    const int lane = tid & 63;
    const int q16  = lane & 15;
    const int quad = lane >> 4;
    const int gid  = blockIdx.x;
    const int bh   = gid & 63;       // XCD co-location for K/V reuse
    const int qblk = gid >> 6;       // 0..7
    const int b    = bh >> 4;
    const int h    = bh & 15;
    const int qtok0 = qblk * 256 + w * 64;

    // Q fragments (pre-scaled by the QKV-GEMM rope epilogue)
    bf16x8 qf[4][2];
    #pragma unroll
    for (int qb = 0; qb < 4; qb++) {
        const short* Qrow =
            qkv + (size_t)(b * SEQ + qtok0 + qb * 16 + q16) * 3072 + h * 64;
        qf[qb][0] = *(const bf16x8*)(Qrow + quad * 8);
        qf[qb][1] = *(const bf16x8*)(Qrow + 32 + quad * 8);
    }

    f32x4 o[4][4];
    #pragma unroll
    for (int qb = 0; qb < 4; qb++)
        #pragma unroll
        for (int md = 0; md < 4; md++) o[qb][md] = (f32x4){0.f, 0.f, 0.f, 0.f};
    float lsum[4] = {0.f, 0.f, 0.f, 0.f};

    const short* Kg = qkv + (size_t)b * SEQ * 3072 + 1024 + h * 64;
    const short* Vg = Kg + 1024;

    // staging constants
    const int krow = w * 16 + (lane >> 3);          // K row this lane fetches
    const int kc   = (lane & 7) ^ (krow & 7);       // swizzled source chunk
    const int vkey = (tid & 31) * 2;                // V: 2 keys per thread
    const int vdb  = (tid >> 5) * 8;                // V: 8 dims per thread
    // pi-permuted logical chunk for this thread's key pair (vkey even ->
    // vkey,vkey+1 share a chunk, at positions vkey&7, (vkey&7)+1)
    const int vL   = ((vkey >> 5) << 2) | (((vkey >> 3) & 1) << 1) | ((vkey >> 4) & 1);

    // V perm-pack + swizzled write: row = vdb+j (row&7 == j), chunk' = vL^j
    auto vwrite = [&](int buf, const uint4& a, const uint4& bb) {
        #pragma unroll
        for (int j = 0; j < 8; j++) {
            unsigned lo = (j & 1) ? 0x07060302u : 0x05040100u;
            unsigned sa = (&a.x)[j >> 1], sb = (&bb.x)[j >> 1];
            *(unsigned*)&Vs[buf][(vdb + j) * 64 + ((vL ^ j) << 3) + (vkey & 7)] =
                __builtin_amdgcn_perm(sb, sa, lo);
        }
    };

    // ---- prologue: stage tile 0 into buf 0 ----
    {
        llds16(Kg + (size_t)krow * 3072 + kc * 8, &Ks[0][(w * 16) * 64]);
        llds16(Kg + (size_t)(krow + 8) * 3072 + kc * 8, &Ks[0][(w * 16 + 8) * 64]);
        const short* vsrc = Vg + (size_t)vkey * 3072 + vdb;
        uint4 a  = *(const uint4*)vsrc;
        uint4 bb = *(const uint4*)(vsrc + 3072);
        vwrite(0, a, bb);
    }
    __syncthreads();

    int cur = 0;
    for (int t = 0; t < SEQ / 64; t++) {
        // prefetch tile t+1 into buf cur^1
        uint4 pva, pvb;
        const bool pf = (t < SEQ / 64 - 1);
        if (pf) {
            const int ktn = (t + 1) * 64;
            llds16(Kg + (size_t)(ktn + krow) * 3072 + kc * 8,
                   &Ks[cur ^ 1][(w * 16) * 64]);
            llds16(Kg + (size_t)(ktn + krow + 8) * 3072 + kc * 8,
                   &Ks[cur ^ 1][(w * 16 + 8) * 64]);
            const short* vsrc = Vg + (size_t)(ktn + vkey) * 3072 + vdb;
            pva = *(const uint4*)vsrc;
            pvb = *(const uint4*)(vsrc + 3072);
        }

        // fragment loads from buf cur (af/av share the address expression)
        bf16x8 af[4][2], av[4][2];
        #pragma unroll
        for (int mb = 0; mb < 4; mb++) {
            #pragma unroll
            for (int ks = 0; ks < 2; ks++) {
                int c = (((ks * 4 + quad) ^ (q16 & 7))) * 8;
                af[mb][ks] = *(const bf16x8*)&Ks[cur][(mb * 16 + q16) * 64 + c];
                av[mb][ks] = *(const bf16x8*)&Vs[cur][(mb * 16 + q16) * 64 + c];
            }
        }

        // qb software pipeline: sc ping-pong, QK(qb+1) issued before the
        // softmax VALU of qb so MFMA and VALU pipes overlap.
        f32x4 sc[2][4];
        #pragma unroll
        for (int mb = 0; mb < 4; mb++) {
            f32x4 c = {0.f, 0.f, 0.f, 0.f};
            c = __builtin_amdgcn_mfma_f32_16x16x32_bf16(af[mb][0], qf[0][0], c, 0, 0, 0);
            c = __builtin_amdgcn_mfma_f32_16x16x32_bf16(af[mb][1], qf[0][1], c, 0, 0, 0);
            sc[0][mb] = c;
        }

        #pragma unroll
        for (int qb = 0; qb < 4; qb++) {
            f32x4* scc = sc[qb & 1];
            f32x4* scn = sc[(qb & 1) ^ 1];
            // next qb's QK first — matrix pipe fills while VALU runs below
            if (qb < 3) {
                #pragma unroll
                for (int mb = 0; mb < 4; mb++) {
                    f32x4 c = {0.f, 0.f, 0.f, 0.f};
                    c = __builtin_amdgcn_mfma_f32_16x16x32_bf16(af[mb][0], qf[qb + 1][0], c, 0, 0, 0);
                    c = __builtin_amdgcn_mfma_f32_16x16x32_bf16(af[mb][1], qf[qb + 1][1], c, 0, 0, 0);
                    scn[mb] = c;
                }
            }
            float ltile = 0.f;
            unsigned da[4], db[4];
            // exp + pack mb 0,1 (keys for PV ks=0)
            #pragma unroll
            for (int mb = 0; mb < 2; mb++) {
                float p0 = __builtin_amdgcn_exp2f(scc[mb][0]);
                float p1 = __builtin_amdgcn_exp2f(scc[mb][1]);
                float p2 = __builtin_amdgcn_exp2f(scc[mb][2]);
                float p3 = __builtin_amdgcn_exp2f(scc[mb][3]);
                ltile += (p0 + p1) + (p2 + p3);
                asm("v_cvt_pk_bf16_f32 %0, %1, %2" : "=v"(da[mb]) : "v"(p0), "v"(p1));
                asm("v_cvt_pk_bf16_f32 %0, %1, %2" : "=v"(db[mb]) : "v"(p2), "v"(p3));
            }
            // in-register quad-pair exchange: vdst rows 1,3 <-> vsrc rows 0,2
            asm("v_permlane16_swap_b32 %0, %1" : "+v"(da[0]), "+v"(da[1]));
            asm("v_permlane16_swap_b32 %0, %1" : "+v"(db[0]), "+v"(db[1]));
            union { u32x4 u; bf16x8 v; } pb0;
            pb0.u = (u32x4){da[0], db[0], da[1], db[1]};
            // exp + pack mb 2,3 (overlaps PV ks=0 below)
            #pragma unroll
            for (int mb = 2; mb < 4; mb++) {
                float p0 = __builtin_amdgcn_exp2f(scc[mb][0]);
                float p1 = __builtin_amdgcn_exp2f(scc[mb][1]);
                float p2 = __builtin_amdgcn_exp2f(scc[mb][2]);
                float p3 = __builtin_amdgcn_exp2f(scc[mb][3]);
                ltile += (p0 + p1) + (p2 + p3);
                asm("v_cvt_pk_bf16_f32 %0, %1, %2" : "=v"(da[mb]) : "v"(p0), "v"(p1));
                asm("v_cvt_pk_bf16_f32 %0, %1, %2" : "=v"(db[mb]) : "v"(p2), "v"(p3));
            }
            // PV ks=0
            #pragma unroll
            for (int md = 0; md < 4; md++)
                o[qb][md] = __builtin_amdgcn_mfma_f32_16x16x32_bf16(
                    av[md][0], pb0.v, o[qb][md], 0, 0, 0);
            asm("v_permlane16_swap_b32 %0, %1" : "+v"(da[2]), "+v"(da[3]));
            asm("v_permlane16_swap_b32 %0, %1" : "+v"(db[2]), "+v"(db[3]));
            union { u32x4 u; bf16x8 v; } pb1;
            pb1.u = (u32x4){da[2], db[2], da[3], db[3]};
            // PV ks=1
            #pragma unroll
            for (int md = 0; md < 4; md++)
                o[qb][md] = __builtin_amdgcn_mfma_f32_16x16x32_bf16(
                    av[md][1], pb1.v, o[qb][md], 0, 0, 0);
            lsum[qb] += ltile;
        }

        // write prefetched V into buf cur^1 after compute
        if (pf) vwrite(cur ^ 1, pva, pvb);
        __syncthreads();
        cur ^= 1;
    }

    // epilogue: cross-quad l reduction, normalize, store bf16
    #pragma unroll
    for (int qb = 0; qb < 4; qb++) {
        float l = lsum[qb];
        l += __shfl_xor(l, 16);
        l += __shfl_xor(l, 32);
        float inv = 1.f / l;
        short* orow = out + (size_t)(b * SEQ + qtok0 + qb * 16 + q16) * 1024
                      + h * 64 + quad * 4;
        #pragma unroll
        for (int md = 0; md < 4; md++) {
            short4v t;
            t[0] = f2bf(o[qb][md][0] * inv);
            t[1] = f2bf(o[qb][md][1] * inv);
            t[2] = f2bf(o[qb][md][2] * inv);
            t[3] = f2bf(o[qb][md][3] * inv);
            *(short4v*)(orow + md * 16) = t;
        }
    }
}

// ---------------------------------------------------------------------------
extern "C" void kernel_launch(void* const* d_in, const int* in_sizes, int n_in,
                              void* d_out, int out_size, void* d_ws, size_t ws_size,
                              hipStream_t stream)
{
    (void)in_sizes; (void)n_in; (void)out_size; (void)ws_size;
    const float* x      = (const float*)d_in[0];
    const int*   p      = (const int*)  d_in[1];
    const float* Wqkv_w = (const float*)d_in[2];
    const float* Wqkv_b = (const float*)d_in[3];
    const float* Wo_w   = (const float*)d_in[4];
    const float* Wo_b   = (const float*)d_in[5];
    float* out = (float*)d_out;

    short* xb     = (short*)d_ws;                         // 16 MiB
    short* wqkvb  = xb + (size_t)TOKENS * 1024;           // 6 MiB
    short* wob    = wqkvb + (size_t)3072 * 1024;          // 2 MiB
    short* qkvb   = wob + (size_t)1024 * 1024;            // 48 MiB
    short* attnob = qkvb + (size_t)TOKENS * 3072;         // 16 MiB

    dim3 blk(256);
    constexpr int GEMM_LDS = 3 * (256 + 128) * 64 * 2;    // 147456 B

    cvt3_bf16_kernel<<<dim3((N8_X + N8_WQKV + N8_WO) / 256), blk, 0, stream>>>(
        x, Wqkv_w, Wo_w, xb, wqkvb, wob);

    static bool attr_done = false;
    if (!attr_done) {
        hipFuncSetAttribute(reinterpret_cast<const void*>(&gemm8p_mfma_kernel<1, 1>),
                            hipFuncAttributeMaxDynamicSharedMemorySize, GEMM_LDS);
        hipFuncSetAttribute(reinterpret_cast<const void*>(&gemm8p_mfma_kernel<0, 0>),
                            hipFuncAttributeMaxDynamicSharedMemorySize, GEMM_LDS);
        attr_done = true;
    }

    // QKV GEMM: M=8192 N=3072 K=1024; 1-D grid 32*24 = 768 (nwg%8==0)
    gemm8p_mfma_kernel<1, 1><<<dim3((TOKENS / 256) * (3072 / 128)), dim3(512),
                               GEMM_LDS, stream>>>(
        xb, wqkvb, Wqkv_b, qkvb, p, TOKENS, 3072, 1024);

    attn_mfma_kernel<<<dim3(512), blk, 0, stream>>>(qkvb, attnob);

    // Wo GEMM: M=8192 N=1024 K=1024; 1-D grid 32*8 = 256 (1 exact round)
    gemm8p_mfma_kernel<0, 0><<<dim3((TOKENS / 256) * (1024 / 128)), dim3(512),
                               GEMM_LDS, stream>>>(
        attnob, wob, Wo_b, out, nullptr, TOKENS, 1024, 1024);
}

// Round 8
// 254.407 us; speedup vs baseline: 1.0312x; 1.0162x over previous
//
#include <hip/hip_runtime.h>
#include <hip/hip_bf16.h>
#include <cmath>

constexpr int D_MODEL = 1024;
constexpr int NHEAD   = 16;
constexpr int DH      = 64;
constexpr int BATCH   = 4;
constexpr int SEQ     = 2048;
constexpr int TOKENS  = BATCH * SEQ;          // 8192
constexpr float SCALE = 0.125f;               // 64^-0.5
// folded into q inside the QKV-GEMM rope epilogue: q' = (SCALE*log2e) * rot(q)
constexpr float QSF   = 0.125f * 1.44269504088896340736f;

typedef __attribute__((ext_vector_type(8))) short bf16x8;
typedef __attribute__((ext_vector_type(4))) short short4v;
typedef __attribute__((ext_vector_type(4))) float f32x4;
typedef __attribute__((ext_vector_type(4))) unsigned u32x4;

__device__ inline short f2bf(float f) {
    union { float f; unsigned u; } v; v.f = f;
    unsigned r = v.u + 0x7FFFu + ((v.u >> 16) & 1u);
    return (short)(r >> 16);
}
__device__ inline float bf2f(short s) {
    union { float f; unsigned u; } v;
    v.u = ((unsigned)(unsigned short)s) << 16;
    return v.f;
}
__device__ inline void llds16(const void* g, void* l) {
    __builtin_amdgcn_global_load_lds(
        (const __attribute__((address_space(1))) unsigned*)g,
        (__attribute__((address_space(3))) unsigned*)l, 16, 0, 0);
}

// ---------------------------------------------------------------------------
// Merged f32 -> bf16 convert for x, Wqkv_w, Wo_w (one launch, 3 segments)
// ---------------------------------------------------------------------------
constexpr int N8_X    = TOKENS * 1024 / 8;    // 1048576
constexpr int N8_WQKV = 3072 * 1024 / 8;      //  393216
constexpr int N8_WO   = 1024 * 1024 / 8;      //  131072

__global__ __launch_bounds__(256) void cvt3_bf16_kernel(
    const float* __restrict__ sx, const float* __restrict__ sq,
    const float* __restrict__ so,
    short* __restrict__ dx, short* __restrict__ dq, short* __restrict__ dw)
{
    int i = blockIdx.x * blockDim.x + threadIdx.x;
    const float* src; short* dst; int off;
    if (i < N8_X)                  { src = sx; dst = dx;  off = i; }
    else if (i < N8_X + N8_WQKV)   { src = sq; dst = dq;  off = i - N8_X; }
    else                           { src = so; dst = dw;  off = i - N8_X - N8_WQKV; }
    const float4* s = (const float4*)src + (size_t)off * 2;
    float4 a = s[0], b = s[1];
    bf16x8 v;
    v[0] = f2bf(a.x); v[1] = f2bf(a.y); v[2] = f2bf(a.z); v[3] = f2bf(a.w);
    v[4] = f2bf(b.x); v[5] = f2bf(b.y); v[6] = f2bf(b.z); v[7] = f2bf(b.w);
    *(bf16x8*)(dst + (size_t)off * 8) = v;
}

// ---------------------------------------------------------------------------
// r12 GEMM (unchanged): counted-vmcnt 3-deep pipeline, XCD-chunked grid.
// BM=256, BN=128, BK=64, 512 thr (8 waves, 4M x 2N). LDS 144KB: 3 bufs.
// vmcnt(12) at the boundary keeps 2 full iterations of slack.
// ---------------------------------------------------------------------------
template<int ROPE, int OUTBF>
__global__ __launch_bounds__(512, 2) void gemm8p_mfma_kernel(
    const short* __restrict__ A, const short* __restrict__ B,
    const float* __restrict__ bias, void* __restrict__ C,
    const int* __restrict__ p, int M, int N, int K)
{
    extern __shared__ short smem[];
    constexpr int BUFSZ = (256 + 128) * 64;   // shorts per buffer

    const int tid  = threadIdx.x;
    const int w    = tid >> 6;
    const int lane = tid & 63;
    const int q16  = lane & 15;
    const int quad = lane >> 4;
    const int wm   = (w >> 1) * 64;    // 0,64,128,192
    const int wn   = (w & 1) * 64;     // 0,64
    const int NT   = K >> 6;

    // XCD-chunked block mapping: grid is 1-D, nwg = GX*GY, GX = M/256.
    const int GX  = M >> 8;
    const int cpx = GX >> 3;                   // bm-chunk per XCD
    const int wg  = blockIdx.x;
    const int xcd = wg & 7;
    const int r_  = wg >> 3;
    const int bm  = (xcd * cpx + (r_ % cpx)) * 256;
    const int bn  = (r_ / cpx) * 128;

    const int rowbase = tid >> 3;      // 0..63
    const int ch      = tid & 7;
    const int chs     = ch ^ (rowbase & 7);  // pre-swizzled source chunk

    auto stage = [&](int buf, int tt) {
        const int k0 = tt * 64;
        short* base  = smem + buf * BUFSZ;
        #pragma unroll
        for (int i = 0; i < 4; i++) {
            int r = i * 64 + rowbase;
            llds16(A + (size_t)(bm + r) * K + k0 + chs * 8,
                   base + r * 64 + ch * 8);
        }
        short* bbase = base + 256 * 64;
        #pragma unroll
        for (int i = 0; i < 2; i++) {
            int r = i * 64 + rowbase;
            llds16(B + (size_t)(bn + r) * K + k0 + chs * 8,
                   bbase + r * 64 + ch * 8);
        }
    };

    f32x4 acc[4][4];
    #pragma unroll
    for (int i = 0; i < 4; i++)
        #pragma unroll
        for (int j = 0; j < 4; j++) acc[i][j] = (f32x4){0.f, 0.f, 0.f, 0.f};

    // prologue: tiles 0,1,2 in flight; drain tile 0 only (12 = 2x6 remain)
    stage(0, 0);
    stage(1, 1);
    stage(2, 2);
    asm volatile("s_waitcnt vmcnt(12)" ::: "memory");
    asm volatile("s_barrier" ::: "memory");

    int c = 0;
    for (int t = 0; t < NT; t++) {
        const short* as = smem + c * BUFSZ;
        const short* bs = as + 256 * 64;

        bf16x8 af[2][4], bfr[2][4];
        #pragma unroll
        for (int ks = 0; ks < 2; ks++) {
            const int sw = (ks * 4 + quad) ^ (q16 & 7);
            #pragma unroll
            for (int i = 0; i < 4; i++) {
                af[ks][i]  = *(const bf16x8*)&as[(wm + i * 16 + q16) * 64 + sw * 8];
                bfr[ks][i] = *(const bf16x8*)&bs[(wn + i * 16 + q16) * 64 + sw * 8];
            }
        }
        __builtin_amdgcn_s_setprio(1);
        #pragma unroll
        for (int ks = 0; ks < 2; ks++)
            #pragma unroll
            for (int mb = 0; mb < 4; mb++)
                #pragma unroll
                for (int nb = 0; nb < 4; nb++)
                    acc[mb][nb] = __builtin_amdgcn_mfma_f32_16x16x32_bf16(
                        af[ks][mb], bfr[ks][nb], acc[mb][nb], 0, 0, 0);
        __builtin_amdgcn_s_setprio(0);

        if (t + 1 < NT) {
            asm volatile("s_waitcnt lgkmcnt(0)" ::: "memory");
            __builtin_amdgcn_sched_barrier(0);
            asm volatile("s_barrier" ::: "memory");       // buf c free
            if (t + 3 < NT) {
                stage(c, t + 3);
                asm volatile("s_waitcnt vmcnt(12)" ::: "memory");
            } else if (t + 2 < NT) {
                asm volatile("s_waitcnt vmcnt(6)" ::: "memory");
            } else {
                asm volatile("s_waitcnt vmcnt(0)" ::: "memory");
            }
            asm volatile("s_barrier" ::: "memory");       // tile t+1 ready
        }
        c = (c == 2) ? 0 : c + 1;
    }

    if (ROPE && (bn + wn) < 2 * D_MODEL) {
        // q or k head: rotate pairs (nb, nb+2) = dims (i, i+32), i = nb*16+q16
        const float sf = (bn + wn) < D_MODEL ? QSF : 1.0f;
        float posv[4][4];
        #pragma unroll
        for (int mb = 0; mb < 4; mb++) {
            const int rm = bm + wm + mb * 16 + quad * 4;
            #pragma unroll
            for (int r = 0; r < 4; r++) posv[mb][r] = (float)p[rm + r];
        }
        #pragma unroll
        for (int nb = 0; nb < 2; nb++) {
            const int i   = nb * 16 + q16;
            const int cn0 = bn + wn + i;
            const int cn1 = cn0 + 32;
            const float b0 = bias[cn0], b1 = bias[cn1];
            const float fr = __builtin_amdgcn_exp2f((float)i * -0.4152410118609203f)
                             * 0.15915494309189535f;
            #pragma unroll
            for (int mb = 0; mb < 4; mb++) {
                const int rm = bm + wm + mb * 16 + quad * 4;
                #pragma unroll
                for (int r = 0; r < 4; r++) {
                    float t = posv[mb][r] * fr;
                    t -= floorf(t);
                    float sn = __builtin_amdgcn_sinf(t);
                    float c2 = __builtin_amdgcn_cosf(t);
                    float v0 = acc[mb][nb][r]     + b0;
                    float v1 = acc[mb][nb + 2][r] + b1;
                    ((short*)C)[(size_t)(rm + r) * N + cn0] =
                        f2bf(fmaf(v0, c2,  v1 * sn) * sf);
                    ((short*)C)[(size_t)(rm + r) * N + cn1] =
                        f2bf(fmaf(v1, c2, -v0 * sn) * sf);
                }
            }
        }
        return;
    }

    #pragma unroll
    for (int nb = 0; nb < 4; nb++) {
        const int cn = bn + wn + nb * 16 + q16;
        const float bv = bias[cn];
        #pragma unroll
        for (int mb = 0; mb < 4; mb++) {
            const int rm = bm + wm + mb * 16 + quad * 4;
            #pragma unroll
            for (int r = 0; r < 4; r++) {
                float v = acc[mb][nb][r] + bv;
                if (OUTBF)
                    ((short*)C)[(size_t)(rm + r) * N + cn] = f2bf(v);
                else
                    ((float*)C)[(size_t)(rm + r) * N + cn] = v;
            }
        }
    }
}

// ---------------------------------------------------------------------------
// MFMA flash attention v9 (r14). Mechanism found in r7 counters: MfmaUtil
// (32%) + VALUBusy (45%) = 77% ~= total issue-busy -> the two pipes have
// ZERO overlap (MFMA-phase then VALU-phase, serial; waves are in-order so a
// back-to-back MFMA cluster blocks later VALU issue). Fix = T19
// sched_group_barrier: pin the program order to {1 MFMA, 3 VALU} x 16 per
// qb body so softmax VALU issues while the matrix pipe executes. The qb
// software pipeline (QK(qb+1) before softmax(qb), sc ping-pong) provides
// the independent streams the interleave needs.
// Unchanged: S^T = K @ Q^T; P in-register (cvt_pk + permlane16_swap, Vs key
// axis pi-permuted); double-buffered K/V; one barrier/tile; no online max
// (bounded scores); bh = gid&63 L2 swizzle; LDS 32KB/block; grid 512.
// ---------------------------------------------------------------------------
__global__ __launch_bounds__(256, 2)
void attn_mfma_kernel(
    const short* __restrict__ qkv, short* __restrict__ out)
{
    __shared__ short Ks[2][64 * 64];   // [buf][key-row][dim-chunk swz]
    __shared__ short Vs[2][64 * 64];   // [buf][dim-row][key-chunk swz, pi-permuted]

    const int tid  = threadIdx.x;
    const int w    = tid >> 6;
    const int lane = tid & 63;
    const int q16  = lane & 15;
    const int quad = lane >> 4;
    const int gid  = blockIdx.x;
    const int bh   = gid & 63;       // XCD co-location for K/V reuse
    const int qblk = gid >> 6;       // 0..7
    const int b    = bh >> 4;
    const int h    = bh & 15;
    const int qtok0 = qblk * 256 + w * 64;

    // Q fragments (pre-scaled by the QKV-GEMM rope epilogue)
    bf16x8 qf[4][2];
    #pragma unroll
    for (int qb = 0; qb < 4; qb++) {
        const short* Qrow =
            qkv + (size_t)(b * SEQ + qtok0 + qb * 16 + q16) * 3072 + h * 64;
        qf[qb][0] = *(const bf16x8*)(Qrow + quad * 8);
        qf[qb][1] = *(const bf16x8*)(Qrow + 32 + quad * 8);
    }

    f32x4 o[4][4];
    #pragma unroll
    for (int qb = 0; qb < 4; qb++)
        #pragma unroll
        for (int md = 0; md < 4; md++) o[qb][md] = (f32x4){0.f, 0.f, 0.f, 0.f};
    float lsum[4] = {0.f, 0.f, 0.f, 0.f};

    const short* Kg = qkv + (size_t)b * SEQ * 3072 + 1024 + h * 64;
    const short* Vg = Kg + 1024;

    // staging constants
    const int krow = w * 16 + (lane >> 3);          // K row this lane fetches
    const int kc   = (lane & 7) ^ (krow & 7);       // swizzled source chunk
    const int vkey = (tid & 31) * 2;                // V: 2 keys per thread
    const int vdb  = (tid >> 5) * 8;                // V: 8 dims per thread
    // pi-permuted logical chunk for this thread's key pair (vkey even ->
    // vkey,vkey+1 share a chunk, at positions vkey&7, (vkey&7)+1)
    const int vL   = ((vkey >> 5) << 2) | (((vkey >> 3) & 1) << 1) | ((vkey >> 4) & 1);

    // V perm-pack + swizzled write: row = vdb+j (row&7 == j), chunk' = vL^j
    auto vwrite = [&](int buf, const uint4& a, const uint4& bb) {
        #pragma unroll
        for (int j = 0; j < 8; j++) {
            unsigned lo = (j & 1) ? 0x07060302u : 0x05040100u;
            unsigned sa = (&a.x)[j >> 1], sb = (&bb.x)[j >> 1];
            *(unsigned*)&Vs[buf][(vdb + j) * 64 + ((vL ^ j) << 3) + (vkey & 7)] =
                __builtin_amdgcn_perm(sb, sa, lo);
        }
    };

    // ---- prologue: stage tile 0 into buf 0 ----
    {
        llds16(Kg + (size_t)krow * 3072 + kc * 8, &Ks[0][(w * 16) * 64]);
        llds16(Kg + (size_t)(krow + 8) * 3072 + kc * 8, &Ks[0][(w * 16 + 8) * 64]);
        const short* vsrc = Vg + (size_t)vkey * 3072 + vdb;
        uint4 a  = *(const uint4*)vsrc;
        uint4 bb = *(const uint4*)(vsrc + 3072);
        vwrite(0, a, bb);
    }
    __syncthreads();

    int cur = 0;
    for (int t = 0; t < SEQ / 64; t++) {
        // prefetch tile t+1 into buf cur^1
        uint4 pva, pvb;
        const bool pf = (t < SEQ / 64 - 1);
        if (pf) {
            const int ktn = (t + 1) * 64;
            llds16(Kg + (size_t)(ktn + krow) * 3072 + kc * 8,
                   &Ks[cur ^ 1][(w * 16) * 64]);
            llds16(Kg + (size_t)(ktn + krow + 8) * 3072 + kc * 8,
                   &Ks[cur ^ 1][(w * 16 + 8) * 64]);
            const short* vsrc = Vg + (size_t)(ktn + vkey) * 3072 + vdb;
            pva = *(const uint4*)vsrc;
            pvb = *(const uint4*)(vsrc + 3072);
        }

        // fragment loads from buf cur (af/av share the address expression)
        bf16x8 af[4][2], av[4][2];
        #pragma unroll
        for (int mb = 0; mb < 4; mb++) {
            #pragma unroll
            for (int ks = 0; ks < 2; ks++) {
                int c = (((ks * 4 + quad) ^ (q16 & 7))) * 8;
                af[mb][ks] = *(const bf16x8*)&Ks[cur][(mb * 16 + q16) * 64 + c];
                av[mb][ks] = *(const bf16x8*)&Vs[cur][(mb * 16 + q16) * 64 + c];
            }
        }

        // qb software pipeline: sc ping-pong, QK(qb+1) issued before the
        // softmax VALU of qb; sched_group_barrier pins {1 MFMA, 3 VALU}.
        f32x4 sc[2][4];
        #pragma unroll
        for (int mb = 0; mb < 4; mb++) {
            f32x4 c = {0.f, 0.f, 0.f, 0.f};
            c = __builtin_amdgcn_mfma_f32_16x16x32_bf16(af[mb][0], qf[0][0], c, 0, 0, 0);
            c = __builtin_amdgcn_mfma_f32_16x16x32_bf16(af[mb][1], qf[0][1], c, 0, 0, 0);
            sc[0][mb] = c;
        }

        #pragma unroll
        for (int qb = 0; qb < 4; qb++) {
            f32x4* scc = sc[qb & 1];
            f32x4* scn = sc[(qb & 1) ^ 1];
            // next qb's QK first — matrix pipe fills while VALU runs below
            if (qb < 3) {
                #pragma unroll
                for (int mb = 0; mb < 4; mb++) {
                    f32x4 c = {0.f, 0.f, 0.f, 0.f};
                    c = __builtin_amdgcn_mfma_f32_16x16x32_bf16(af[mb][0], qf[qb + 1][0], c, 0, 0, 0);
                    c = __builtin_amdgcn_mfma_f32_16x16x32_bf16(af[mb][1], qf[qb + 1][1], c, 0, 0, 0);
                    scn[mb] = c;
                }
            }
            float ltile = 0.f;
            unsigned da[4], db[4];
            // exp + pack mb 0,1 (keys for PV ks=0)
            #pragma unroll
            for (int mb = 0; mb < 2; mb++) {
                float p0 = __builtin_amdgcn_exp2f(scc[mb][0]);
                float p1 = __builtin_amdgcn_exp2f(scc[mb][1]);
                float p2 = __builtin_amdgcn_exp2f(scc[mb][2]);
                float p3 = __builtin_amdgcn_exp2f(scc[mb][3]);
                ltile += (p0 + p1) + (p2 + p3);
                asm("v_cvt_pk_bf16_f32 %0, %1, %2" : "=v"(da[mb]) : "v"(p0), "v"(p1));
                asm("v_cvt_pk_bf16_f32 %0, %1, %2" : "=v"(db[mb]) : "v"(p2), "v"(p3));
            }
            // in-register quad-pair exchange: vdst rows 1,3 <-> vsrc rows 0,2
            asm("v_permlane16_swap_b32 %0, %1" : "+v"(da[0]), "+v"(da[1]));
            asm("v_permlane16_swap_b32 %0, %1" : "+v"(db[0]), "+v"(db[1]));
            union { u32x4 u; bf16x8 v; } pb0;
            pb0.u = (u32x4){da[0], db[0], da[1], db[1]};
            // exp + pack mb 2,3 (overlaps PV ks=0 below)
            #pragma unroll
            for (int mb = 2; mb < 4; mb++) {
                float p0 = __builtin_amdgcn_exp2f(scc[mb][0]);
                float p1 = __builtin_amdgcn_exp2f(scc[mb][1]);
                float p2 = __builtin_amdgcn_exp2f(scc[mb][2]);
                float p3 = __builtin_amdgcn_exp2f(scc[mb][3]);
                ltile += (p0 + p1) + (p2 + p3);
                asm("v_cvt_pk_bf16_f32 %0, %1, %2" : "=v"(da[mb]) : "v"(p0), "v"(p1));
                asm("v_cvt_pk_bf16_f32 %0, %1, %2" : "=v"(db[mb]) : "v"(p2), "v"(p3));
            }
            // PV ks=0
            #pragma unroll
            for (int md = 0; md < 4; md++)
                o[qb][md] = __builtin_amdgcn_mfma_f32_16x16x32_bf16(
                    av[md][0], pb0.v, o[qb][md], 0, 0, 0);
            asm("v_permlane16_swap_b32 %0, %1" : "+v"(da[2]), "+v"(da[3]));
            asm("v_permlane16_swap_b32 %0, %1" : "+v"(db[2]), "+v"(db[3]));
            union { u32x4 u; bf16x8 v; } pb1;
            pb1.u = (u32x4){da[2], db[2], da[3], db[3]};
            // PV ks=1
            #pragma unroll
            for (int md = 0; md < 4; md++)
                o[qb][md] = __builtin_amdgcn_mfma_f32_16x16x32_bf16(
                    av[md][1], pb1.v, o[qb][md], 0, 0, 0);
            lsum[qb] += ltile;

            // T19: pin {1 MFMA, 3 VALU} interleave for this qb body.
            // qb<3: 16 MFMA (8 QK-next + 8 PV) among ~48 VALU (exp/cvt/
            // permlane/adds). qb==3: 8 MFMA (PV only), richer VALU ratio.
            if (qb < 3) {
                #pragma unroll
                for (int g = 0; g < 16; g++) {
                    __builtin_amdgcn_sched_group_barrier(0x008, 1, 0); // MFMA
                    __builtin_amdgcn_sched_group_barrier(0x002, 3, 0); // VALU
                }
            } else {
                #pragma unroll
                for (int g = 0; g < 8; g++) {
                    __builtin_amdgcn_sched_group_barrier(0x008, 1, 0); // MFMA
                    __builtin_amdgcn_sched_group_barrier(0x002, 6, 0); // VALU
                }
            }
        }

        // write prefetched V into buf cur^1 after compute
        if (pf) vwrite(cur ^ 1, pva, pvb);
        __syncthreads();
        cur ^= 1;
    }

    // epilogue: cross-quad l reduction, normalize, store bf16
    #pragma unroll
    for (int qb = 0; qb < 4; qb++) {
        float l = lsum[qb];
        l += __shfl_xor(l, 16);
        l += __shfl_xor(l, 32);
        float inv = 1.f / l;
        short* orow = out + (size_t)(b * SEQ + qtok0 + qb * 16 + q16) * 1024
                      + h * 64 + quad * 4;
        #pragma unroll
        for (int md = 0; md < 4; md++) {
            short4v t;
            t[0] = f2bf(o[qb][md][0] * inv);
            t[1] = f2bf(o[qb][md][1] * inv);
            t[2] = f2bf(o[qb][md][2] * inv);
            t[3] = f2bf(o[qb][md][3] * inv);
            *(short4v*)(orow + md * 16) = t;
        }
    }
}

// ---------------------------------------------------------------------------
extern "C" void kernel_launch(void* const* d_in, const int* in_sizes, int n_in,
                              void* d_out, int out_size, void* d_ws, size_t ws_size,
                              hipStream_t stream)
{
    (void)in_sizes; (void)n_in; (void)out_size; (void)ws_size;
    const float* x      = (const float*)d_in[0];
    const int*   p      = (const int*)  d_in[1];
    const float* Wqkv_w = (const float*)d_in[2];
    const float* Wqkv_b = (const float*)d_in[3];
    const float* Wo_w   = (const float*)d_in[4];
    const float* Wo_b   = (const float*)d_in[5];
    float* out = (float*)d_out;

    short* xb     = (short*)d_ws;                         // 16 MiB
    short* wqkvb  = xb + (size_t)TOKENS * 1024;           // 6 MiB
    short* wob    = wqkvb + (size_t)3072 * 1024;          // 2 MiB
    short* qkvb   = wob + (size_t)1024 * 1024;            // 48 MiB
    short* attnob = qkvb + (size_t)TOKENS * 3072;         // 16 MiB

    dim3 blk(256);
    constexpr int GEMM_LDS = 3 * (256 + 128) * 64 * 2;    // 147456 B

    cvt3_bf16_kernel<<<dim3((N8_X + N8_WQKV + N8_WO) / 256), blk, 0, stream>>>(
        x, Wqkv_w, Wo_w, xb, wqkvb, wob);

    static bool attr_done = false;
    if (!attr_done) {
        hipFuncSetAttribute(reinterpret_cast<const void*>(&gemm8p_mfma_kernel<1, 1>),
                            hipFuncAttributeMaxDynamicSharedMemorySize, GEMM_LDS);
        hipFuncSetAttribute(reinterpret_cast<const void*>(&gemm8p_mfma_kernel<0, 0>),
                            hipFuncAttributeMaxDynamicSharedMemorySize, GEMM_LDS);
        attr_done = true;
    }

    // QKV GEMM: M=8192 N=3072 K=1024; 1-D grid 32*24 = 768 (nwg%8==0)
    gemm8p_mfma_kernel<1, 1><<<dim3((TOKENS / 256) * (3072 / 128)), dim3(512),
                               GEMM_LDS, stream>>>(
        xb, wqkvb, Wqkv_b, qkvb, p, TOKENS, 3072, 1024);

    attn_mfma_kernel<<<dim3(512), blk, 0, stream>>>(qkvb, attnob);

    // Wo GEMM: M=8192 N=1024 K=1024; 1-D grid 32*8 = 256 (1 exact round)
    gemm8p_mfma_kernel<0, 0><<<dim3((TOKENS / 256) * (1024 / 128)), dim3(512),
                               GEMM_LDS, stream>>>(
        attnob, wob, Wo_b, out, nullptr, TOKENS, 1024, 1024);
}